// Round 10
// baseline (305.311 us; speedup 1.0000x reference)
//
#include <hip/hip_runtime.h>

// Fused GQA attention block: QKV proj(+RoPE, +V-transpose) -> flash attn -> out proj.
// B=2 S=2048 D=2048 H=16 KV=4 HD=128. All MFMA compute in bf16 (tol = 2% of max).

#define B_  2
#define S_  2048
#define D_  2048
#define H_  16
#define KV_ 4
#define HD_ 128
#define NQK 2560    // QK buffer row stride: 2048 (Q) + 512 (K); V goes to Vt directly

typedef unsigned short ushort_t;
typedef __attribute__((ext_vector_type(8))) __bf16 bf16x8;
typedef __attribute__((ext_vector_type(4))) float  f32x4;

__device__ __forceinline__ ushort_t f2bf(float f) {
    unsigned u = __float_as_uint(f);
    u += 0x7FFFu + ((u >> 16) & 1u);          // round-to-nearest-even
    return (ushort_t)(u >> 16);
}
// compiler-native cast (emits v_cvt_pk_bf16_f32, RNE) — 1 op vs 4 for f2bf
__device__ __forceinline__ ushort_t f2bf_fast(float f) {
    __bf16 h = (__bf16)f;
    return *(ushort_t*)&h;
}
__device__ __forceinline__ float bf2f(ushort_t h) {
    return __uint_as_float(((unsigned)h) << 16);
}

// async global->LDS, 16B per lane; LDS dest = wave-uniform base + lane*16
__device__ __forceinline__ void g2l16(const void* g, void* l) {
    __builtin_amdgcn_global_load_lds(
        (const __attribute__((address_space(1))) unsigned int*)g,
        (__attribute__((address_space(3))) unsigned int*)l, 16, 0, 0);
}

// softmax scale 1/sqrt(128)*log2(e), folded into gemm1's Q epilogue (r6)
#define SOFTSC 0.12751743f

// ---------------- fused prep: x->bf16, 4 weight transposes, bias pack -------

__global__ __launch_bounds__(256) void k_prep(
    const float* __restrict__ x,  ushort_t* __restrict__ xb,
    const float* __restrict__ Wq, const float* __restrict__ Wk,
    const float* __restrict__ Wv, const float* __restrict__ Wo,
    ushort_t* __restrict__ Wt, ushort_t* __restrict__ Wot,
    const float* __restrict__ bq, const float* __restrict__ bk,
    const float* __restrict__ bv, float* __restrict__ bb) {
    __shared__ float tile[32][33];
    int id = blockIdx.x, t = threadIdx.x;
    if (id < 8192) {                                   // x fp32 -> bf16
        int i = id * 256 + t;
        float4 v = ((const float4*)x)[i];
        ushort4 o;
        o.x = f2bf(v.x); o.y = f2bf(v.y); o.z = f2bf(v.z); o.w = f2bf(v.w);
        ((ushort4*)xb)[i] = o;
        return;
    }
    const float* src; ushort_t* dst; int C, bid;
    if (id < 12288)      { src = Wq; dst = Wt;                       C = 2048; bid = id - 8192;  }
    else if (id < 13312) { src = Wk; dst = Wt + (size_t)2048 * 2048; C = 512;  bid = id - 12288; }
    else if (id < 14336) { src = Wv; dst = Wt + (size_t)2560 * 2048; C = 512;  bid = id - 13312; }
    else if (id < 18432) { src = Wo; dst = Wot;                      C = 2048; bid = id - 14336; }
    else {                                             // bias pack
        int i = (id - 18432) * 256 + t;
        if (i < 3072)
            bb[i] = (i < 2048) ? bq[i] : (i < 2560) ? bk[i - 2048] : bv[i - 2560];
        return;
    }
    const int R = 2048;
    int nbc = C >> 5;
    int c0 = (bid % nbc) * 32, r0 = (bid / nbc) * 32;
    int tx = t & 31, ty = t >> 5;
    for (int i = ty; i < 32; i += 8)
        tile[i][tx] = src[(size_t)(r0 + i) * C + c0 + tx];
    __syncthreads();
    for (int i = ty; i < 32; i += 8)
        dst[(size_t)(c0 + i) * R + r0 + tx] = f2bf(tile[tx][i]);
}

// ---------------- gemm2: 128x128 tile, 2-phase -------------------------------
// r9: BK 128 -> 64. BK=128's 64KB LDS is the documented regression config
// (m132: 874->508 TF, occupancy loss beats barrier amortization). BK=64 =
// 32KB LDS, 3 blocks/CU -- the exact structure that measured 706 TF as r1's
// gemm1. Grid unchanged (512 = 32mt x 16nt, %8==0 bijective swizzle).

template<int BK>
__global__ __launch_bounds__(256, 3) void k_gemm(const ushort_t* __restrict__ A,
                                                 const ushort_t* __restrict__ Bt,
                                                 void* __restrict__ Cp,
                                                 const float* __restrict__ bias,
                                                 const float* __restrict__ fc,
                                                 const float* __restrict__ fs,
                                                 ushort_t* __restrict__ Vt,
                                                 int M, int N, int K, int out_bf16) {
    constexpr int GPR    = BK / 8;    // 16B granules per row
    constexpr int RPR    = 64 / GPR;  // rows staged per round per wave
    constexpr int ROUNDS = 32 / RPR;  // rounds to cover 32 rows per wave
    __shared__ __align__(16) ushort_t As[128 * BK];
    __shared__ __align__(16) ushort_t Bs[128 * BK];
    int t = threadIdx.x;
    int w = t >> 6, lane = t & 63, quad = lane >> 4, l16 = lane & 15;
    int L = blockIdx.x;
    int mper = (M >> 7) >> 3;                 // m-tiles per XCD
    int xcd = L & 7, j = L >> 3;
    int m0 = (xcd * mper + (j % mper)) * 128;
    int n0 = (j / mper) * 128;
    int wm = (w >> 1) * 64, wn = (w & 1) * 64;
    f32x4 acc[4][4] = {};

    int rlo = lane / GPR;                     // row-within-round
    int gsl = lane & (GPR - 1);               // slot granule
    const ushort_t* Ag = A  + (size_t)(m0 + w * 32) * K;
    const ushort_t* Bg = Bt + (size_t)(n0 + w * 32) * K;
    int rsw = (l16 & 7);                      // read-side swizzle bits

    for (int k0 = 0; k0 < K; k0 += BK) {
        __syncthreads();
#pragma unroll
        for (int p = 0; p < ROUNDS; p++) {
            int row = p * RPR + rlo;
            int gs = gsl ^ (row & 7);
            g2l16(Ag + (size_t)row * K + k0 + gs * 8, (char*)As + (w * 32 + p * RPR) * 2 * BK);
            g2l16(Bg + (size_t)row * K + k0 + gs * 8, (char*)Bs + (w * 32 + p * RPR) * 2 * BK);
        }
        __syncthreads();
#pragma unroll
        for (int kc = 0; kc < BK / 32; kc++) {
            int gg = quad + kc * 4;
            bf16x8 af[4], bfr[4];
#pragma unroll
            for (int i = 0; i < 4; i++)
                af[i] = *(const bf16x8*)(As + (wm + i * 16 + l16) * BK + ((gg ^ rsw) * 8));
#pragma unroll
            for (int j2 = 0; j2 < 4; j2++)
                bfr[j2] = *(const bf16x8*)(Bs + (wn + j2 * 16 + l16) * BK + ((gg ^ rsw) * 8));
#pragma unroll
            for (int i = 0; i < 4; i++)
#pragma unroll
                for (int j2 = 0; j2 < 4; j2++)
                    acc[i][j2] = __builtin_amdgcn_mfma_f32_16x16x32_bf16(af[i], bfr[j2], acc[i][j2], 0, 0, 0);
        }
    }
    int ostride = fc ? NQK : N;
#pragma unroll
    for (int i = 0; i < 4; i++) {
        int r = m0 + wm + i * 16 + quad * 4;
#pragma unroll
        for (int j2 = 0; j2 < 4; j2++) {
            int c = n0 + wn + j2 * 16 + l16;
            float bv_ = bias ? bias[c] : 0.f;
            if (fc && c >= 2560) {
                ushort4 pack;
                pack.x = f2bf(acc[i][j2][0] + bv_);
                pack.y = f2bf(acc[i][j2][1] + bv_);
                pack.z = f2bf(acc[i][j2][2] + bv_);
                pack.w = f2bf(acc[i][j2][3] + bv_);
                int kv = (c - 2560) >> 7, d = (c - 2560) & 127;
                int b = r >> 11, s0 = r & (S_ - 1);
                *(ushort4*)&Vt[(((size_t)b * KV_ + kv) * HD_ + d) * S_ + s0] = pack;
                continue;
            }
#pragma unroll
            for (int jr = 0; jr < 4; jr++) {
                float v = acc[i][j2][jr] + bv_;
                if (fc) {
                    int s  = (r + jr) & (S_ - 1);
                    int dp = (c & 127) >> 1;
                    float cs = fc[s * 64 + dp], sn = fs[s * 64 + dp];
                    float p = __shfl_xor(v, 1);
                    v = (c & 1) ? (v * cs + p * sn) : (v * cs - p * sn);
                }
                if (out_bf16) ((ushort_t*)Cp)[(size_t)(r + jr) * ostride + c] = f2bf(v);
                else          ((float*)Cp)[(size_t)(r + jr) * ostride + c] = v;
            }
        }
    }
}

// ---------------- gemm1: 128x192 tile, 2 blocks/CU, v5 ----------------------
// (r8: occupancy-first redesign; 80KB LDS -> 2 blocks/CU, 512 blocks,
// 2 barriers/tile, counted vmcnt. Measured ~64us. See r8 notes.)

#define G1_K  2048
#define G1_NT 32

__global__ __launch_bounds__(512, 4) void k_gemm1_256(
    const ushort_t* __restrict__ A, const ushort_t* __restrict__ Bt,
    ushort_t* __restrict__ C, const float* __restrict__ bias,
    const float* __restrict__ fc, const float* __restrict__ fs,
    ushort_t* __restrict__ Vt) {
    __shared__ __align__(16) ushort_t As[2][8192];    // 2 bufs x 128 rows x 64
    __shared__ __align__(16) ushort_t Bs[2][12288];   // 2 bufs x 192 rows x 64
    int t = threadIdx.x;
    int w = t >> 6, lane = t & 63, quad = lane >> 4, l16 = lane & 15;
    int wm_i = w >> 2, wn_i = w & 3;

    int L = blockIdx.x;                    // 32 mt x 16 nt, m striped per XCD
    int xcd = L & 7, j = L >> 3;           // mper = 32/8 = 4
    int m0 = (xcd * 4 + (j & 3)) * 128;
    int n0 = (j >> 2) * 192;

    int srow = w * 8 + (lane >> 3);
    int sg   = (lane & 7) ^ (lane >> 3);
    const ushort_t* Ag  = A  + (size_t)(m0 + srow) * G1_K + sg * 8;
    const ushort_t* Bg3 = Bt + (size_t)(n0 + srow) * G1_K + sg * 8;

    int swz = l16 & 7;
    int cA = (quad ^ swz) * 8;             // kc=0 chunk (elem offset in row)
    int cB = ((quad + 4) ^ swz) * 8;       // kc=1

    f32x4 acc[4][3] = {};
    bf16x8 afr[4][2], bf_[2];

#define ST_A(KT, HA, BUF) do {                                                  \
    const ushort_t* s_ = Ag + (size_t)(HA) * 64 * G1_K + (KT) * 64;             \
    char* d_ = (char*)&As[BUF][(HA) * 4096] + w * 1024;                         \
    g2l16(s_, d_); } while (0)
#define ST_B(KT, G, BUF) do {                                                   \
    const ushort_t* s_ = Bg3 + (size_t)(G) * 64 * G1_K + (KT) * 64;             \
    char* d_ = (char*)&Bs[BUF][(G) * 4096] + w * 1024;                          \
    g2l16(s_, d_); } while (0)

#define RDA(BUF) do {                                                           \
    const ushort_t* Ar = &As[BUF][(wm_i * 64 + l16) * 64];                      \
    _Pragma("unroll") for (int ii = 0; ii < 4; ii++) {                          \
        afr[ii][0] = *(const bf16x8*)(Ar + ii * 1024 + cA);                     \
        afr[ii][1] = *(const bf16x8*)(Ar + ii * 1024 + cB); } } while (0)
#define RDB(G, BUF) do {                                                        \
    const ushort_t* Br = &Bs[BUF][(wn_i * 48 + (G) * 16 + l16) * 64];           \
    bf_[0] = *(const bf16x8*)(Br + cA);                                         \
    bf_[1] = *(const bf16x8*)(Br + cB); } while (0)

#define MMA(G) do {                                                             \
    _Pragma("unroll") for (int kc = 0; kc < 2; kc++)                            \
    _Pragma("unroll") for (int ii = 0; ii < 4; ii++)                            \
        acc[ii][G] = __builtin_amdgcn_mfma_f32_16x16x32_bf16(                   \
            afr[ii][kc], bf_[kc], acc[ii][G], 0, 0, 0); } while (0)

#define BAR1() __builtin_amdgcn_s_barrier()
#define LGKM0() do { asm volatile("s_waitcnt lgkmcnt(0)" ::: "memory");         \
                     __builtin_amdgcn_sched_barrier(0); } while (0)

#define TILE(KT, BUF, OTH) do {                                                 \
    /* P1 */                                                                    \
    if ((KT) + 1 < G1_NT) { ST_A((KT) + 1, 0, OTH); ST_B((KT) + 1, 0, OTH); }   \
    RDA(BUF); RDB(0, BUF);                                                      \
    LGKM0();                                                                    \
    __builtin_amdgcn_s_setprio(1); MMA(0); __builtin_amdgcn_s_setprio(0);       \
    /* P2 */                                                                    \
    if ((KT) + 1 < G1_NT) { ST_A((KT) + 1, 1, OTH); ST_B((KT) + 1, 1, OTH); }   \
    RDB(1, BUF);                                                                \
    LGKM0();                                                                    \
    __builtin_amdgcn_s_setprio(1); MMA(1); __builtin_amdgcn_s_setprio(0);       \
    /* P3 */                                                                    \
    if ((KT) + 1 < G1_NT) ST_B((KT) + 1, 2, OTH);                               \
    if ((KT) + 1 < G1_NT) asm volatile("s_waitcnt vmcnt(1)" ::: "memory");      \
    else                  asm volatile("s_waitcnt vmcnt(0)" ::: "memory");      \
    BAR1();                                                                     \
    RDB(2, BUF);                                                                \
    LGKM0();                                                                    \
    __builtin_amdgcn_s_setprio(1); MMA(2); __builtin_amdgcn_s_setprio(0);       \
    BAR1();                                                                     \
} while (0)

    // prologue: tile0 {A0,A1,B0,B1,B2} -> buf0 (5 loads/thread), full drain.
    ST_A(0, 0, 0); ST_A(0, 1, 0);
    ST_B(0, 0, 0); ST_B(0, 1, 0); ST_B(0, 2, 0);
    asm volatile("s_waitcnt vmcnt(0)" ::: "memory");
    BAR1();

    for (int kt = 0; kt < G1_NT; kt += 2) {
        TILE(kt, 0, 1);
        TILE(kt + 1, 1, 0);
    }
#undef ST_A
#undef ST_B
#undef RDA
#undef RDB
#undef MMA
#undef BAR1
#undef LGKM0
#undef TILE

    // epilogue: frag (i,j2) -> r = m0+wm_i*64+i*16+quad*4, c = n0+wn_i*48+j2*16+l16
#pragma unroll
    for (int i = 0; i < 4; i++) {
        int r = m0 + wm_i * 64 + i * 16 + quad * 4;
#pragma unroll
        for (int j2 = 0; j2 < 3; j2++) {
            int c = n0 + wn_i * 48 + j2 * 16 + l16;
            float bv_ = bias[c];
            if (c >= 2560) {                          // V cols -> transposed Vt
                ushort4 pack;
                pack.x = f2bf(acc[i][j2][0] + bv_);
                pack.y = f2bf(acc[i][j2][1] + bv_);
                pack.z = f2bf(acc[i][j2][2] + bv_);
                pack.w = f2bf(acc[i][j2][3] + bv_);
                int kv = (c - 2560) >> 7, d = (c - 2560) & 127;
                int b = r >> 11, s0 = r & (S_ - 1);
                *(ushort4*)&Vt[(((size_t)b * KV_ + kv) * HD_ + d) * S_ + s0] = pack;
                continue;
            }
#pragma unroll
            for (int jr = 0; jr < 4; jr++) {
                float v = acc[i][j2][jr] + bv_;
                int s  = (r + jr) & (S_ - 1);
                int dp = (c & 127) >> 1;
                float cs = fc[s * 64 + dp], sn = fs[s * 64 + dp];
                float p = __shfl_xor(v, 1);           // pair element (c^1)
                v = (c & 1) ? (v * cs + p * sn) : (v * cs - p * sn);
                if (c < 2048) v *= SOFTSC;            // fold softmax scale into Q
                C[(size_t)(r + jr) * NQK + c] = f2bf(v);
            }
        }
    }
}

// ---------------- Flash attention v6: P-LDS swizzle + lean softmax ----------
// (r6: P XOR-swizzle fixed 3.78M bank-conflict cycles; SOFTSC folded into Q;
// native bf16 cast in P-write. r8 counters: conflicts 0, 65.3us.)

__global__ __launch_bounds__(512, 4) void k_flash(const ushort_t* __restrict__ QK,
                                                  const ushort_t* __restrict__ Vt,
                                                  ushort_t* __restrict__ AO) {
    __shared__ __align__(16) ushort_t Ks[2 * 8192];
    __shared__ __align__(16) ushort_t Vs[2 * 8192];
    __shared__ __align__(16) ushort_t Ps[8 * 16 * 64];
    int h = blockIdx.y, b = blockIdx.z;
    int qt = b ? ((int)gridDim.x - 1 - (int)blockIdx.x) : (int)blockIdx.x;
    int kvh = h >> 2;
    int t = threadIdx.x, w = t >> 6, lane = t & 63, quad = lane >> 4, l16 = lane & 15;
    int qrow0 = qt * 128 + w * 16;

    bf16x8 aq[4];
    {
        const ushort_t* qb = QK + (size_t)(b * S_ + qrow0 + l16) * NQK + h * HD_ + quad * 8;
#pragma unroll
        for (int kc = 0; kc < 4; kc++) aq[kc] = *(const bf16x8*)(qb + kc * 32);
    }
    bf16x8 vone;
#pragma unroll
    for (int i = 0; i < 8; i++) vone[i] = (__bf16)1.0f;

    f32x4 o[8] = {};
    f32x4 ol = {};                 // row-sum accumulator (softmax denominator)
    ushort_t* Psw = Ps + w * 16 * 64;
    int gsw = (l16 >> 1) & 3;      // K/V read-side swizzle bits

    const ushort_t* kgb = QK + (size_t)(b * S_) * NQK + 2048 + kvh * HD_;
    const ushort_t* vgb = Vt + ((size_t)(b * KV_ + kvh) * HD_) * S_;

    int sr, sgs; char *sK0, *sV0;
    if (t < 256) {
        sr = t >> 2; sgs = (t & 3) ^ ((sr >> 1) & 3);
        sK0 = (char*)Ks + (t >> 6) * 1024;
        sV0 = nullptr;
    } else {
        int u = t - 256;
        sr = u >> 2; sgs = (u & 3) ^ ((sr >> 1) & 3);
        sV0 = (char*)Vs + ((t - 256) >> 6) * 1024;
        sK0 = nullptr;
    }

#define STAGE(KT, BUF)                                                          \
    do {                                                                        \
        if (t < 256) {                                                          \
            const ushort_t* kg = kgb + (size_t)((KT) * 64 + sr) * NQK + sgs * 8; \
            char* KsW = sK0 + (BUF) * 16384;                                    \
            _Pragma("unroll")                                                   \
            for (int p = 0; p < 4; p++) g2l16(kg + p * 32, KsW + p * 4096);     \
        } else {                                                                \
            const ushort_t* vg = vgb + (KT) * 64 + sgs * 8 + (size_t)sr * S_;   \
            char* VsW = sV0 + (BUF) * 16384;                                    \
            _Pragma("unroll")                                                   \
            for (int p = 0; p < 4; p++)                                         \
                g2l16(vg + (size_t)((p & 1) * 64) * S_ + (p >> 1) * 32, VsW + p * 4096); \
        }                                                                       \
    } while (0)

    int ktmax = 2 * qt + 1;
    STAGE(0, 0);
    __syncthreads();

    for (int kt = 0; kt <= ktmax; kt++) {
        int cur = kt & 1;
        if (kt < ktmax) STAGE(kt + 1, cur ^ 1);   // prefetch next tile

        if (kt * 64 <= qrow0 + 15) {              // else fully-masked for this wave
            const ushort_t* Kc = Ks + cur * 8192;
            const ushort_t* Vc = Vs + cur * 8192;
            f32x4 sacc[4] = {};
            __builtin_amdgcn_s_setprio(1);        // T5: favor MFMA wave (m191)
#pragma unroll
            for (int kc = 0; kc < 4; kc++)
#pragma unroll
                for (int nb = 0; nb < 4; nb++) {
                    bf16x8 bk = *(const bf16x8*)(Kc + kc * 2048 + (nb * 16 + l16) * 32 + ((quad ^ gsw) * 8));
                    sacc[nb] = __builtin_amdgcn_mfma_f32_16x16x32_bf16(aq[kc], bk, sacc[nb], 0, 0, 0);
                }
            __builtin_amdgcn_s_setprio(0);
            if (kt * 64 + 63 > qrow0) {           // diagonal tile: causal mask
#pragma unroll
                for (int nb = 0; nb < 4; nb++)
#pragma unroll
                    for (int jr = 0; jr < 4; jr++) {
                        int kcol = kt * 64 + nb * 16 + l16;
                        int qr = qrow0 + quad * 4 + jr;
                        if (kcol > qr) sacc[nb][jr] = -1e30f;
                    }
            }
            // P write, granule-swizzled: slot (key>>3)^(q&7) of row q
#pragma unroll
            for (int nb = 0; nb < 4; nb++)
#pragma unroll
                for (int jr = 0; jr < 4; jr++) {
                    int q  = quad * 4 + jr;
                    int gi = (nb * 2 + (l16 >> 3)) ^ (q & 7);
                    Psw[q * 64 + gi * 8 + (l16 & 7)] = f2bf_fast(exp2f(sacc[nb][jr]));
                }

            asm volatile("s_waitcnt lgkmcnt(0)" ::: "memory");  // P writes -> A-frag reads

            __builtin_amdgcn_s_setprio(1);        // T5: favor MFMA wave (m191)
#pragma unroll
            for (int kc2 = 0; kc2 < 2; kc2++) {
                bf16x8 ap = *(const bf16x8*)(Psw + l16 * 64 + (((kc2 * 4 + quad) ^ (l16 & 7)) * 8));
                ol = __builtin_amdgcn_mfma_f32_16x16x32_bf16(ap, vone, ol, 0, 0, 0);
#pragma unroll
                for (int db = 0; db < 8; db++) {
                    bf16x8 bv = *(const bf16x8*)(Vc + kc2 * 4096 + (db * 16 + l16) * 32 + ((quad ^ gsw) * 8));
                    o[db] = __builtin_amdgcn_mfma_f32_16x16x32_bf16(ap, bv, o[db], 0, 0, 0);
                }
            }
            __builtin_amdgcn_s_setprio(0);
        }
        __syncthreads();   // next tile staged + this tile's LDS reads done
    }
#undef STAGE

    // epilogue: divide by l, write bf16
#pragma unroll
    for (int jr = 0; jr < 4; jr++) {
        float inv = 1.0f / ol[jr];
        size_t rbase = (size_t)(b * S_ + qrow0 + quad * 4 + jr) * D_ + h * HD_;
#pragma unroll
        for (int db = 0; db < 8; db++)
            AO[rbase + db * 16 + l16] = f2bf(o[db][jr] * inv);
    }
}

// ---------------- launch ----------------

extern "C" void kernel_launch(void* const* d_in, const int* in_sizes, int n_in,
                              void* d_out, int out_size, void* d_ws, size_t ws_size,
                              hipStream_t stream) {
    const float* x  = (const float*)d_in[0];
    // d_in[1] = mask (all zeros; reference ignores it — causal built in-kernel)
    const float* fc = (const float*)d_in[2];
    const float* fs = (const float*)d_in[3];
    const float* Wq = (const float*)d_in[4];
    const float* bq = (const float*)d_in[5];
    const float* Wk = (const float*)d_in[6];
    const float* bk = (const float*)d_in[7];
    const float* Wv = (const float*)d_in[8];
    const float* bv = (const float*)d_in[9];
    const float* Wo = (const float*)d_in[10];

    char* ws = (char*)d_ws;
    // layout (bytes); AO aliases xb (xb dead after gemm1). Vt is its own 4 MB
    // (must NOT alias Wt: gemm1 reads Wt while writing Vt). QK stride 2560.
    ushort_t* xb  = (ushort_t*)(ws);                 // 16 MB  (4096x2048 bf16)
    ushort_t* Wt  = (ushort_t*)(ws + 16777216);      // 12 MB  (3072x2048 bf16)
    ushort_t* Wot = (ushort_t*)(ws + 29360128);      //  8 MB  (2048x2048 bf16)
    float*    bb  = (float*)   (ws + 37748736);      // 12 KB
    ushort_t* QK  = (ushort_t*)(ws + 37761024);      // 20 MB  (4096x2560 bf16)
    ushort_t* Vt  = (ushort_t*)(ws + 58732544);      //  4 MB  (2*4*128*2048 bf16)
    ushort_t* AO  = xb;                              // 16 MB  (4096x2048 bf16)
    float* out = (float*)d_out;

    k_prep<<<18444, 256, 0, stream>>>(x, xb, Wq, Wk, Wv, Wo, Wt, Wot, bq, bk, bv, bb);
    k_gemm1_256<<<512, 512, 0, stream>>>(xb, Wt, QK, bb, fc, fs, Vt);
    k_flash<<<dim3(16, 16, 2), 512, 0, stream>>>(QK, Vt, AO);
    k_gemm<64><<<512, 256, 0, stream>>>(AO, Wot, out, nullptr, nullptr, nullptr, nullptr,
                                        4096, 2048, 2048, 0);
}

// Round 12
// 298.543 us; speedup vs baseline: 1.0227x; 1.0227x over previous
//
#include <hip/hip_runtime.h>

// Fused GQA attention block: QKV proj(+RoPE, +V-transpose) -> flash attn -> out proj.
// B=2 S=2048 D=2048 H=16 KV=4 HD=128. All MFMA compute in bf16 (tol = 2% of max).

#define B_  2
#define S_  2048
#define D_  2048
#define H_  16
#define KV_ 4
#define HD_ 128
#define NQK 2560    // QK buffer row stride: 2048 (Q) + 512 (K); V goes to Vt directly

typedef unsigned short ushort_t;
typedef __attribute__((ext_vector_type(8))) __bf16 bf16x8;
typedef __attribute__((ext_vector_type(4))) float  f32x4;

__device__ __forceinline__ ushort_t f2bf(float f) {
    unsigned u = __float_as_uint(f);
    u += 0x7FFFu + ((u >> 16) & 1u);          // round-to-nearest-even
    return (ushort_t)(u >> 16);
}
// compiler-native cast (emits v_cvt_pk_bf16_f32, RNE) — 1 op vs 4 for f2bf
__device__ __forceinline__ ushort_t f2bf_fast(float f) {
    __bf16 h = (__bf16)f;
    return *(ushort_t*)&h;
}
__device__ __forceinline__ float bf2f(ushort_t h) {
    return __uint_as_float(((unsigned)h) << 16);
}

// async global->LDS, 16B per lane; LDS dest = wave-uniform base + lane*16
__device__ __forceinline__ void g2l16(const void* g, void* l) {
    __builtin_amdgcn_global_load_lds(
        (const __attribute__((address_space(1))) unsigned int*)g,
        (__attribute__((address_space(3))) unsigned int*)l, 16, 0, 0);
}

// softmax scale 1/sqrt(128)*log2(e), folded into gemm1's Q epilogue (r6)
#define SOFTSC 0.12751743f

// ---------------- fused prep: x->bf16, 4 weight transposes, bias pack -------

__global__ __launch_bounds__(256) void k_prep(
    const float* __restrict__ x,  ushort_t* __restrict__ xb,
    const float* __restrict__ Wq, const float* __restrict__ Wk,
    const float* __restrict__ Wv, const float* __restrict__ Wo,
    ushort_t* __restrict__ Wt, ushort_t* __restrict__ Wot,
    const float* __restrict__ bq, const float* __restrict__ bk,
    const float* __restrict__ bv, float* __restrict__ bb) {
    __shared__ float tile[32][33];
    int id = blockIdx.x, t = threadIdx.x;
    if (id < 8192) {                                   // x fp32 -> bf16
        int i = id * 256 + t;
        float4 v = ((const float4*)x)[i];
        ushort4 o;
        o.x = f2bf(v.x); o.y = f2bf(v.y); o.z = f2bf(v.z); o.w = f2bf(v.w);
        ((ushort4*)xb)[i] = o;
        return;
    }
    const float* src; ushort_t* dst; int C, bid;
    if (id < 12288)      { src = Wq; dst = Wt;                       C = 2048; bid = id - 8192;  }
    else if (id < 13312) { src = Wk; dst = Wt + (size_t)2048 * 2048; C = 512;  bid = id - 12288; }
    else if (id < 14336) { src = Wv; dst = Wt + (size_t)2560 * 2048; C = 512;  bid = id - 13312; }
    else if (id < 18432) { src = Wo; dst = Wot;                      C = 2048; bid = id - 14336; }
    else {                                             // bias pack
        int i = (id - 18432) * 256 + t;
        if (i < 3072)
            bb[i] = (i < 2048) ? bq[i] : (i < 2560) ? bk[i - 2048] : bv[i - 2560];
        return;
    }
    const int R = 2048;
    int nbc = C >> 5;
    int c0 = (bid % nbc) * 32, r0 = (bid / nbc) * 32;
    int tx = t & 31, ty = t >> 5;
    for (int i = ty; i < 32; i += 8)
        tile[i][tx] = src[(size_t)(r0 + i) * C + c0 + tx];
    __syncthreads();
    for (int i = ty; i < 32; i += 8)
        dst[(size_t)(c0 + i) * R + r0 + tx] = f2bf(tile[tx][i]);
}

// ---------------- gemm2: 128x128 tile, 2-phase -------------------------------
// r10 post-mortem: BK=64 flip was NEUTRAL-to-negative (total 302.6->305.3);
// the "gemm2 = 68us" budget theory was wrong (r6 top-5 cutoff already bounded
// it <65us; the budget residual is harness memset/launch overhead).
// r11: reverted to BK=128 (r8's measured-best config).

template<int BK>
__global__ __launch_bounds__(256, 3) void k_gemm(const ushort_t* __restrict__ A,
                                                 const ushort_t* __restrict__ Bt,
                                                 void* __restrict__ Cp,
                                                 const float* __restrict__ bias,
                                                 const float* __restrict__ fc,
                                                 const float* __restrict__ fs,
                                                 ushort_t* __restrict__ Vt,
                                                 int M, int N, int K, int out_bf16) {
    constexpr int GPR    = BK / 8;    // 16B granules per row
    constexpr int RPR    = 64 / GPR;  // rows staged per round per wave
    constexpr int ROUNDS = 32 / RPR;  // rounds to cover 32 rows per wave
    __shared__ __align__(16) ushort_t As[128 * BK];
    __shared__ __align__(16) ushort_t Bs[128 * BK];
    int t = threadIdx.x;
    int w = t >> 6, lane = t & 63, quad = lane >> 4, l16 = lane & 15;
    int L = blockIdx.x;
    int mper = (M >> 7) >> 3;                 // m-tiles per XCD
    int xcd = L & 7, j = L >> 3;
    int m0 = (xcd * mper + (j % mper)) * 128;
    int n0 = (j / mper) * 128;
    int wm = (w >> 1) * 64, wn = (w & 1) * 64;
    f32x4 acc[4][4] = {};

    int rlo = lane / GPR;                     // row-within-round
    int gsl = lane & (GPR - 1);               // slot granule
    const ushort_t* Ag = A  + (size_t)(m0 + w * 32) * K;
    const ushort_t* Bg = Bt + (size_t)(n0 + w * 32) * K;
    int rsw = (l16 & 7);                      // read-side swizzle bits

    for (int k0 = 0; k0 < K; k0 += BK) {
        __syncthreads();
#pragma unroll
        for (int p = 0; p < ROUNDS; p++) {
            int row = p * RPR + rlo;
            int gs = gsl ^ (row & 7);
            g2l16(Ag + (size_t)row * K + k0 + gs * 8, (char*)As + (w * 32 + p * RPR) * 2 * BK);
            g2l16(Bg + (size_t)row * K + k0 + gs * 8, (char*)Bs + (w * 32 + p * RPR) * 2 * BK);
        }
        __syncthreads();
#pragma unroll
        for (int kc = 0; kc < BK / 32; kc++) {
            int gg = quad + kc * 4;
            bf16x8 af[4], bfr[4];
#pragma unroll
            for (int i = 0; i < 4; i++)
                af[i] = *(const bf16x8*)(As + (wm + i * 16 + l16) * BK + ((gg ^ rsw) * 8));
#pragma unroll
            for (int j2 = 0; j2 < 4; j2++)
                bfr[j2] = *(const bf16x8*)(Bs + (wn + j2 * 16 + l16) * BK + ((gg ^ rsw) * 8));
#pragma unroll
            for (int i = 0; i < 4; i++)
#pragma unroll
                for (int j2 = 0; j2 < 4; j2++)
                    acc[i][j2] = __builtin_amdgcn_mfma_f32_16x16x32_bf16(af[i], bfr[j2], acc[i][j2], 0, 0, 0);
        }
    }
    int ostride = fc ? NQK : N;
#pragma unroll
    for (int i = 0; i < 4; i++) {
        int r = m0 + wm + i * 16 + quad * 4;
#pragma unroll
        for (int j2 = 0; j2 < 4; j2++) {
            int c = n0 + wn + j2 * 16 + l16;
            float bv_ = bias ? bias[c] : 0.f;
            if (fc && c >= 2560) {
                ushort4 pack;
                pack.x = f2bf(acc[i][j2][0] + bv_);
                pack.y = f2bf(acc[i][j2][1] + bv_);
                pack.z = f2bf(acc[i][j2][2] + bv_);
                pack.w = f2bf(acc[i][j2][3] + bv_);
                int kv = (c - 2560) >> 7, d = (c - 2560) & 127;
                int b = r >> 11, s0 = r & (S_ - 1);
                *(ushort4*)&Vt[(((size_t)b * KV_ + kv) * HD_ + d) * S_ + s0] = pack;
                continue;
            }
#pragma unroll
            for (int jr = 0; jr < 4; jr++) {
                float v = acc[i][j2][jr] + bv_;
                if (fc) {
                    int s  = (r + jr) & (S_ - 1);
                    int dp = (c & 127) >> 1;
                    float cs = fc[s * 64 + dp], sn = fs[s * 64 + dp];
                    float p = __shfl_xor(v, 1);
                    v = (c & 1) ? (v * cs + p * sn) : (v * cs - p * sn);
                }
                if (out_bf16) ((ushort_t*)Cp)[(size_t)(r + jr) * ostride + c] = f2bf(v);
                else          ((float*)Cp)[(size_t)(r + jr) * ostride + c] = v;
            }
        }
    }
}

// ---------------- gemm1: 128x192 tile, 2 blocks/CU, v5 ----------------------
// (r8: occupancy-first redesign; 80KB LDS -> 2 blocks/CU, 512 blocks,
// 2 barriers/tile, counted vmcnt. Measured ~64us. Frozen.)

#define G1_K  2048
#define G1_NT 32

__global__ __launch_bounds__(512, 4) void k_gemm1_256(
    const ushort_t* __restrict__ A, const ushort_t* __restrict__ Bt,
    ushort_t* __restrict__ C, const float* __restrict__ bias,
    const float* __restrict__ fc, const float* __restrict__ fs,
    ushort_t* __restrict__ Vt) {
    __shared__ __align__(16) ushort_t As[2][8192];    // 2 bufs x 128 rows x 64
    __shared__ __align__(16) ushort_t Bs[2][12288];   // 2 bufs x 192 rows x 64
    int t = threadIdx.x;
    int w = t >> 6, lane = t & 63, quad = lane >> 4, l16 = lane & 15;
    int wm_i = w >> 2, wn_i = w & 3;

    int L = blockIdx.x;                    // 32 mt x 16 nt, m striped per XCD
    int xcd = L & 7, j = L >> 3;           // mper = 32/8 = 4
    int m0 = (xcd * 4 + (j & 3)) * 128;
    int n0 = (j >> 2) * 192;

    int srow = w * 8 + (lane >> 3);
    int sg   = (lane & 7) ^ (lane >> 3);
    const ushort_t* Ag  = A  + (size_t)(m0 + srow) * G1_K + sg * 8;
    const ushort_t* Bg3 = Bt + (size_t)(n0 + srow) * G1_K + sg * 8;

    int swz = l16 & 7;
    int cA = (quad ^ swz) * 8;             // kc=0 chunk (elem offset in row)
    int cB = ((quad + 4) ^ swz) * 8;       // kc=1

    f32x4 acc[4][3] = {};
    bf16x8 afr[4][2], bf_[2];

#define ST_A(KT, HA, BUF) do {                                                  \
    const ushort_t* s_ = Ag + (size_t)(HA) * 64 * G1_K + (KT) * 64;             \
    char* d_ = (char*)&As[BUF][(HA) * 4096] + w * 1024;                         \
    g2l16(s_, d_); } while (0)
#define ST_B(KT, G, BUF) do {                                                   \
    const ushort_t* s_ = Bg3 + (size_t)(G) * 64 * G1_K + (KT) * 64;             \
    char* d_ = (char*)&Bs[BUF][(G) * 4096] + w * 1024;                          \
    g2l16(s_, d_); } while (0)

#define RDA(BUF) do {                                                           \
    const ushort_t* Ar = &As[BUF][(wm_i * 64 + l16) * 64];                      \
    _Pragma("unroll") for (int ii = 0; ii < 4; ii++) {                          \
        afr[ii][0] = *(const bf16x8*)(Ar + ii * 1024 + cA);                     \
        afr[ii][1] = *(const bf16x8*)(Ar + ii * 1024 + cB); } } while (0)
#define RDB(G, BUF) do {                                                        \
    const ushort_t* Br = &Bs[BUF][(wn_i * 48 + (G) * 16 + l16) * 64];           \
    bf_[0] = *(const bf16x8*)(Br + cA);                                         \
    bf_[1] = *(const bf16x8*)(Br + cB); } while (0)

#define MMA(G) do {                                                             \
    _Pragma("unroll") for (int kc = 0; kc < 2; kc++)                            \
    _Pragma("unroll") for (int ii = 0; ii < 4; ii++)                            \
        acc[ii][G] = __builtin_amdgcn_mfma_f32_16x16x32_bf16(                   \
            afr[ii][kc], bf_[kc], acc[ii][G], 0, 0, 0); } while (0)

#define BAR1() __builtin_amdgcn_s_barrier()
#define LGKM0() do { asm volatile("s_waitcnt lgkmcnt(0)" ::: "memory");         \
                     __builtin_amdgcn_sched_barrier(0); } while (0)

#define TILE(KT, BUF, OTH) do {                                                 \
    /* P1 */                                                                    \
    if ((KT) + 1 < G1_NT) { ST_A((KT) + 1, 0, OTH); ST_B((KT) + 1, 0, OTH); }   \
    RDA(BUF); RDB(0, BUF);                                                      \
    LGKM0();                                                                    \
    __builtin_amdgcn_s_setprio(1); MMA(0); __builtin_amdgcn_s_setprio(0);       \
    /* P2 */                                                                    \
    if ((KT) + 1 < G1_NT) { ST_A((KT) + 1, 1, OTH); ST_B((KT) + 1, 1, OTH); }   \
    RDB(1, BUF);                                                                \
    LGKM0();                                                                    \
    __builtin_amdgcn_s_setprio(1); MMA(1); __builtin_amdgcn_s_setprio(0);       \
    /* P3 */                                                                    \
    if ((KT) + 1 < G1_NT) ST_B((KT) + 1, 2, OTH);                               \
    if ((KT) + 1 < G1_NT) asm volatile("s_waitcnt vmcnt(1)" ::: "memory");      \
    else                  asm volatile("s_waitcnt vmcnt(0)" ::: "memory");      \
    BAR1();                                                                     \
    RDB(2, BUF);                                                                \
    LGKM0();                                                                    \
    __builtin_amdgcn_s_setprio(1); MMA(2); __builtin_amdgcn_s_setprio(0);       \
    BAR1();                                                                     \
} while (0)

    // prologue: tile0 {A0,A1,B0,B1,B2} -> buf0 (5 loads/thread), full drain.
    ST_A(0, 0, 0); ST_A(0, 1, 0);
    ST_B(0, 0, 0); ST_B(0, 1, 0); ST_B(0, 2, 0);
    asm volatile("s_waitcnt vmcnt(0)" ::: "memory");
    BAR1();

    for (int kt = 0; kt < G1_NT; kt += 2) {
        TILE(kt, 0, 1);
        TILE(kt + 1, 1, 0);
    }
#undef ST_A
#undef ST_B
#undef RDA
#undef RDB
#undef MMA
#undef BAR1
#undef LGKM0
#undef TILE

    // epilogue: frag (i,j2) -> r = m0+wm_i*64+i*16+quad*4, c = n0+wn_i*48+j2*16+l16
#pragma unroll
    for (int i = 0; i < 4; i++) {
        int r = m0 + wm_i * 64 + i * 16 + quad * 4;
#pragma unroll
        for (int j2 = 0; j2 < 3; j2++) {
            int c = n0 + wn_i * 48 + j2 * 16 + l16;
            float bv_ = bias[c];
            if (c >= 2560) {                          // V cols -> transposed Vt
                ushort4 pack;
                pack.x = f2bf(acc[i][j2][0] + bv_);
                pack.y = f2bf(acc[i][j2][1] + bv_);
                pack.z = f2bf(acc[i][j2][2] + bv_);
                pack.w = f2bf(acc[i][j2][3] + bv_);
                int kv = (c - 2560) >> 7, d = (c - 2560) & 127;
                int b = r >> 11, s0 = r & (S_ - 1);
                *(ushort4*)&Vt[(((size_t)b * KV_ + kv) * HD_ + d) * S_ + s0] = pack;
                continue;
            }
#pragma unroll
            for (int jr = 0; jr < 4; jr++) {
                float v = acc[i][j2][jr] + bv_;
                int s  = (r + jr) & (S_ - 1);
                int dp = (c & 127) >> 1;
                float cs = fc[s * 64 + dp], sn = fs[s * 64 + dp];
                float p = __shfl_xor(v, 1);           // pair element (c^1)
                v = (c & 1) ? (v * cs + p * sn) : (v * cs - p * sn);
                if (c < 2048) v *= SOFTSC;            // fold softmax scale into Q
                C[(size_t)(r + jr) * NQK + c] = f2bf(v);
            }
        }
    }
}

// ---------------- Flash attention v7: split-P half-pipelines ----------------
// r11 delta vs v6 (counters: MfmaUtil 23 + VALU 34.6 = 58% busy, 42% idle;
// softmax VALU serial between QK and PV MFMA clusters behind one lgkm(0)):
// P chunk arithmetic: chunk = key>>3 = nb*2+(l16>>3), so nb=0,1 write exactly
// the logical granules PV kc2=0 reads, nb=2,3 those of kc2=1. Split into two
// half-pipelines: write P(nb01) -> lgkm0 -> PV kc2=0 cluster; write P(nb23)
// WHILE kc2=0 MFMAs execute -> lgkm0 -> PV kc2=1. Each wait covers 8 writes;
// ~half the softmax VALU overlaps the MFMA pipe within the wave.
// Hazard audit (r11): for every row r the XOR-by-(r&7) swizzle maps half-A's
// read set and half-B's write set into OPPOSITE physical granule halves ->
// disjoint addresses; per-wave DS in-order + private Psw region => safe.

__global__ __launch_bounds__(512, 4) void k_flash(const ushort_t* __restrict__ QK,
                                                  const ushort_t* __restrict__ Vt,
                                                  ushort_t* __restrict__ AO) {
    __shared__ __align__(16) ushort_t Ks[2 * 8192];
    __shared__ __align__(16) ushort_t Vs[2 * 8192];
    __shared__ __align__(16) ushort_t Ps[8 * 16 * 64];
    int h = blockIdx.y, b = blockIdx.z;
    int qt = b ? ((int)gridDim.x - 1 - (int)blockIdx.x) : (int)blockIdx.x;
    int kvh = h >> 2;
    int t = threadIdx.x, w = t >> 6, lane = t & 63, quad = lane >> 4, l16 = lane & 15;
    int qrow0 = qt * 128 + w * 16;

    bf16x8 aq[4];
    {
        const ushort_t* qb = QK + (size_t)(b * S_ + qrow0 + l16) * NQK + h * HD_ + quad * 8;
#pragma unroll
        for (int kc = 0; kc < 4; kc++) aq[kc] = *(const bf16x8*)(qb + kc * 32);
    }
    bf16x8 vone;
#pragma unroll
    for (int i = 0; i < 8; i++) vone[i] = (__bf16)1.0f;

    f32x4 o[8] = {};
    f32x4 ol = {};                 // row-sum accumulator (softmax denominator)
    ushort_t* Psw = Ps + w * 16 * 64;
    int gsw = (l16 >> 1) & 3;      // K/V read-side swizzle bits

    const ushort_t* kgb = QK + (size_t)(b * S_) * NQK + 2048 + kvh * HD_;
    const ushort_t* vgb = Vt + ((size_t)(b * KV_ + kvh) * HD_) * S_;

    int sr, sgs; char *sK0, *sV0;
    if (t < 256) {
        sr = t >> 2; sgs = (t & 3) ^ ((sr >> 1) & 3);
        sK0 = (char*)Ks + (t >> 6) * 1024;
        sV0 = nullptr;
    } else {
        int u = t - 256;
        sr = u >> 2; sgs = (u & 3) ^ ((sr >> 1) & 3);
        sV0 = (char*)Vs + ((t - 256) >> 6) * 1024;
        sK0 = nullptr;
    }

#define STAGE(KT, BUF)                                                          \
    do {                                                                        \
        if (t < 256) {                                                          \
            const ushort_t* kg = kgb + (size_t)((KT) * 64 + sr) * NQK + sgs * 8; \
            char* KsW = sK0 + (BUF) * 16384;                                    \
            _Pragma("unroll")                                                   \
            for (int p = 0; p < 4; p++) g2l16(kg + p * 32, KsW + p * 4096);     \
        } else {                                                                \
            const ushort_t* vg = vgb + (KT) * 64 + sgs * 8 + (size_t)sr * S_;   \
            char* VsW = sV0 + (BUF) * 16384;                                    \
            _Pragma("unroll")                                                   \
            for (int p = 0; p < 4; p++)                                         \
                g2l16(vg + (size_t)((p & 1) * 64) * S_ + (p >> 1) * 32, VsW + p * 4096); \
        }                                                                       \
    } while (0)

// write P for one nb block (granule-swizzled: chunk nb*2+(l16>>3) ^ (q&7))
#define PWRITE(NB)                                                              \
    _Pragma("unroll")                                                           \
    for (int jr = 0; jr < 4; jr++) {                                            \
        int q  = quad * 4 + jr;                                                 \
        int gi = ((NB) * 2 + (l16 >> 3)) ^ (q & 7);                             \
        Psw[q * 64 + gi * 8 + (l16 & 7)] = f2bf_fast(exp2f(sacc[NB][jr]));      \
    }

    int ktmax = 2 * qt + 1;
    STAGE(0, 0);
    __syncthreads();

    for (int kt = 0; kt <= ktmax; kt++) {
        int cur = kt & 1;
        if (kt < ktmax) STAGE(kt + 1, cur ^ 1);   // prefetch next tile

        if (kt * 64 <= qrow0 + 15) {              // else fully-masked for this wave
            const ushort_t* Kc = Ks + cur * 8192;
            const ushort_t* Vc = Vs + cur * 8192;
            f32x4 sacc[4] = {};
            __builtin_amdgcn_s_setprio(1);        // T5: favor MFMA wave (m191)
#pragma unroll
            for (int kc = 0; kc < 4; kc++)
#pragma unroll
                for (int nb = 0; nb < 4; nb++) {
                    bf16x8 bk = *(const bf16x8*)(Kc + kc * 2048 + (nb * 16 + l16) * 32 + ((quad ^ gsw) * 8));
                    sacc[nb] = __builtin_amdgcn_mfma_f32_16x16x32_bf16(aq[kc], bk, sacc[nb], 0, 0, 0);
                }
            __builtin_amdgcn_s_setprio(0);
            if (kt * 64 + 63 > qrow0) {           // diagonal tile: causal mask
#pragma unroll
                for (int nb = 0; nb < 4; nb++)
#pragma unroll
                    for (int jr = 0; jr < 4; jr++) {
                        int kcol = kt * 64 + nb * 16 + l16;
                        int qr = qrow0 + quad * 4 + jr;
                        if (kcol > qr) sacc[nb][jr] = -1e30f;
                    }
            }
            // half A: P chunks 0-3 (keys 0-31)
            PWRITE(0); PWRITE(1);
            asm volatile("s_waitcnt lgkmcnt(0)" ::: "memory");
            __builtin_amdgcn_sched_barrier(0);
            __builtin_amdgcn_s_setprio(1);
            {
                bf16x8 ap = *(const bf16x8*)(Psw + l16 * 64 + (((0 * 4 + quad) ^ (l16 & 7)) * 8));
                ol = __builtin_amdgcn_mfma_f32_16x16x32_bf16(ap, vone, ol, 0, 0, 0);
#pragma unroll
                for (int db = 0; db < 8; db++) {
                    bf16x8 bv = *(const bf16x8*)(Vc + 0 * 4096 + (db * 16 + l16) * 32 + ((quad ^ gsw) * 8));
                    o[db] = __builtin_amdgcn_mfma_f32_16x16x32_bf16(ap, bv, o[db], 0, 0, 0);
                }
            }
            __builtin_amdgcn_s_setprio(0);
            // half B: P chunks 4-7 (keys 32-63) — VALU overlaps kc2=0 MFMAs
            PWRITE(2); PWRITE(3);
            asm volatile("s_waitcnt lgkmcnt(0)" ::: "memory");
            __builtin_amdgcn_sched_barrier(0);
            __builtin_amdgcn_s_setprio(1);
            {
                bf16x8 ap = *(const bf16x8*)(Psw + l16 * 64 + (((1 * 4 + quad) ^ (l16 & 7)) * 8));
                ol = __builtin_amdgcn_mfma_f32_16x16x32_bf16(ap, vone, ol, 0, 0, 0);
#pragma unroll
                for (int db = 0; db < 8; db++) {
                    bf16x8 bv = *(const bf16x8*)(Vc + 1 * 4096 + (db * 16 + l16) * 32 + ((quad ^ gsw) * 8));
                    o[db] = __builtin_amdgcn_mfma_f32_16x16x32_bf16(ap, bv, o[db], 0, 0, 0);
                }
            }
            __builtin_amdgcn_s_setprio(0);
        }
        __syncthreads();   // next tile staged + this tile's LDS reads done
    }
#undef STAGE
#undef PWRITE

    // epilogue: divide by l, write bf16
#pragma unroll
    for (int jr = 0; jr < 4; jr++) {
        float inv = 1.0f / ol[jr];
        size_t rbase = (size_t)(b * S_ + qrow0 + quad * 4 + jr) * D_ + h * HD_;
#pragma unroll
        for (int db = 0; db < 8; db++)
            AO[rbase + db * 16 + l16] = f2bf(o[db][jr] * inv);
    }
}

// ---------------- launch ----------------

extern "C" void kernel_launch(void* const* d_in, const int* in_sizes, int n_in,
                              void* d_out, int out_size, void* d_ws, size_t ws_size,
                              hipStream_t stream) {
    const float* x  = (const float*)d_in[0];
    // d_in[1] = mask (all zeros; reference ignores it — causal built in-kernel)
    const float* fc = (const float*)d_in[2];
    const float* fs = (const float*)d_in[3];
    const float* Wq = (const float*)d_in[4];
    const float* bq = (const float*)d_in[5];
    const float* Wk = (const float*)d_in[6];
    const float* bk = (const float*)d_in[7];
    const float* Wv = (const float*)d_in[8];
    const float* bv = (const float*)d_in[9];
    const float* Wo = (const float*)d_in[10];

    char* ws = (char*)d_ws;
    // layout (bytes); AO aliases xb (xb dead after gemm1). Vt is its own 4 MB
    // (must NOT alias Wt: gemm1 reads Wt while writing Vt). QK stride 2560.
    ushort_t* xb  = (ushort_t*)(ws);                 // 16 MB  (4096x2048 bf16)
    ushort_t* Wt  = (ushort_t*)(ws + 16777216);      // 12 MB  (3072x2048 bf16)
    ushort_t* Wot = (ushort_t*)(ws + 29360128);      //  8 MB  (2048x2048 bf16)
    float*    bb  = (float*)   (ws + 37748736);      // 12 KB
    ushort_t* QK  = (ushort_t*)(ws + 37761024);      // 20 MB  (4096x2560 bf16)
    ushort_t* Vt  = (ushort_t*)(ws + 58732544);      //  4 MB  (2*4*128*2048 bf16)
    ushort_t* AO  = xb;                              // 16 MB  (4096x2048 bf16)
    float* out = (float*)d_out;

    k_prep<<<18444, 256, 0, stream>>>(x, xb, Wq, Wk, Wv, Wo, Wt, Wot, bq, bk, bv, bb);
    k_gemm1_256<<<512, 512, 0, stream>>>(xb, Wt, QK, bb, fc, fs, Vt);
    k_flash<<<dim3(16, 16, 2), 512, 0, stream>>>(QK, Vt, AO);
    k_gemm<128><<<512, 256, 0, stream>>>(AO, Wot, out, nullptr, nullptr, nullptr, nullptr,
                                         4096, 2048, 2048, 0);
}